// Round 13
// baseline (62.655 us; speedup 1.0000x reference)
//
#include <hip/hip_runtime.h>
#include <hip/hip_bf16.h>
#include <cstdint>

#define B_ROWS 8192
#define DIM    1024
#define NC     8
#define NXCD   8
#define SLOTS  16    // per-XCD 128-row tile slots
#define BM     128
#define BN     64
#define NT     16    // K tiles (DIM/64)

typedef __bf16 bf16;
typedef __bf16 bf16x4 __attribute__((ext_vector_type(4)));
typedef __bf16 bf16x8 __attribute__((ext_vector_type(8)));
typedef float  f32x4  __attribute__((ext_vector_type(4)));

typedef __attribute__((address_space(3))) void* lds_vp;
typedef const __attribute__((address_space(1))) void* gbl_vp;

#define BUFB 24576   // LDS bytes per buffer: (128+64)*64*2
#define ABYT 16384   // A region bytes: 128*64*2

// ---------------- fused prep: block 0 = route, blocks 1..256 = x cvt -------
#define XF4 (B_ROWS * DIM / 4)   // 2097152 float4 in x
__global__ __launch_bounds__(1024) void prep_kernel(
    const float* __restrict__ x, const int* __restrict__ ids,
    const float* __restrict__ b, bf16* __restrict__ xb,
    int* __restrict__ row_list, int* __restrict__ xmeta,
    float* __restrict__ bias_sum) {
    if (blockIdx.x != 0) {
        // fp32 -> bf16 for x only (W is consumed fp32-direct by the GEMM)
        size_t base = (size_t)(blockIdx.x - 1) * 8192 + threadIdx.x;
        const float4* src = (const float4*)x;
        float4 v[8];
#pragma unroll
        for (int k = 0; k < 8; k++) v[k] = src[base + (size_t)k * 1024];
#pragma unroll
        for (int k = 0; k < 8; k++) {
            bf16x4 o;
            o[0] = (bf16)v[k].x; o[1] = (bf16)v[k].y;
            o[2] = (bf16)v[k].z; o[3] = (bf16)v[k].w;
            *(bf16x4*)(xb + 4 * (base + (size_t)k * 1024)) = o;
        }
        return;
    }
    // routing (block 0): 1024 threads, scan-based, no atomics
    __shared__ int wtot_s[16][NC];
    __shared__ int cnt_s[NC];
    __shared__ int off_s[NC];
    __shared__ int used_s[NXCD];
    __shared__ int novf_s[NC];
    int tid = threadIdx.x, lane = tid & 63, wv = tid >> 6;
    const int per = B_ROWS / 1024;  // 8
    int base = tid * per;

    if (tid < NXCD * SLOTS) xmeta[tid * 3 + 2] = 0;

    const int4* idv = (const int4*)(ids + base);
    int4 v0 = idv[0], v1 = idv[1];
    int myid[8] = {v0.x, v0.y, v0.z, v0.w, v1.x, v1.y, v1.z, v1.w};
    unsigned long long p0 = 0, p1 = 0;
#pragma unroll
    for (int q = 0; q < 8; q++) {
        int id = myid[q];
        unsigned long long one = 1ull << ((id & 3) << 4);
        if (id < 4) p0 += one; else p1 += one;
    }
    unsigned long long i0 = p0, i1 = p1;
#pragma unroll
    for (int d = 1; d < 64; d <<= 1) {
        unsigned long long u0 = __shfl_up(i0, d, 64);
        unsigned long long u1 = __shfl_up(i1, d, 64);
        if (lane >= d) { i0 += u0; i1 += u1; }
    }
    unsigned long long e0 = i0 - p0, e1 = i1 - p1;
    unsigned long long t0 = __shfl(i0, 63, 64), t1 = __shfl(i1, 63, 64);
    if (lane == 0) {
#pragma unroll
        for (int c = 0; c < 4; c++) {
            wtot_s[wv][c]     = (int)((t0 >> (c << 4)) & 0xFFFF);
            wtot_s[wv][c + 4] = (int)((t1 >> (c << 4)) & 0xFFFF);
        }
    }
    __syncthreads();
    if (tid < NC) {
        int acc = 0;
        for (int w2 = 0; w2 < 16; w2++) { int t = wtot_s[w2][tid]; wtot_s[w2][tid] = acc; acc += t; }
        cnt_s[tid] = acc;
    }
    __syncthreads();
    if (tid < NC) {
        int acc = 0;
        for (int c2 = 0; c2 < tid; c2++) acc += cnt_s[c2];
        off_s[tid] = acc;
    }
    __syncthreads();
    if (tid < 16 * NC) wtot_s[tid >> 3][tid & 7] += off_s[tid & 7];
    __syncthreads();

    if (tid < NC) {  // primary 128-row tiles: condition c -> XCD c
        int c = tid, n = cnt_s[c];
        int tc = (n + BM - 1) >> 7;
        int prim = tc < SLOTS ? tc : SLOTS;
        for (int t = 0; t < prim; t++) {
            int* e = xmeta + (c * SLOTS + t) * 3;
            int rc = n - t * BM; if (rc > BM) rc = BM;
            e[0] = c; e[1] = off_s[c] + t * BM; e[2] = rc;
        }
        used_s[c] = prim;
        novf_s[c] = tc - prim;
    }
    {
        float s = 0.f;
#pragma unroll
        for (int c = 0; c < NC; c++) s += b[c * DIM + tid];
        bias_sum[tid] = s;
    }
    __syncthreads();
    if (tid == 0) {  // overflow tiles (condition with >SLOTS*128 rows)
        int k = 0;
        for (int c = 0; c < NC; c++) {
            for (int t = 0; t < novf_s[c]; t++) {
                for (;;) {
                    int xx = k >> 4, s = k & (SLOTS - 1); k++;
                    if (s >= used_s[xx]) {
                        int* e = xmeta + (xx * SLOTS + s) * 3;
                        int rc = cnt_s[c] - (SLOTS + t) * BM; if (rc > BM) rc = BM;
                        e[0] = c; e[1] = off_s[c] + (SLOTS + t) * BM; e[2] = rc;
                        break;
                    }
                }
            }
        }
    }
    unsigned long long r0 = 0, r1 = 0;
#pragma unroll
    for (int j = 0; j < per; j++) {
        int id = myid[j];
        int sh = (id & 3) << 4;
        unsigned long long run = (id < 4) ? r0 : r1;
        unsigned long long exc = (id < 4) ? e0 : e1;
        int p = wtot_s[wv][id] + (int)((exc >> sh) & 0xFFFF) + (int)((run >> sh) & 0xFFFF);
        row_list[p] = base + j;
        unsigned long long one = 1ull << sh;
        if (id < 4) r0 += one; else r1 += one;
    }
}

// ---------------- grouped GEMM: 128x64, 4 waves, 3 blocks/CU ---------------
// A: bf16 via global_load_lds (pre-swizzled source). B: fp32 W reg-staged,
// cvt to bf16, swizzled ds_write (same phys-granule convention as A).
// vm queue per step t: [A(t) 4, BL(t+1) 4, A(t+1) 4]; gates vmcnt(8)/vmcnt(4).
__global__ __launch_bounds__(256, 3) void gemm_kernel(
    const bf16* __restrict__ xb, const float* __restrict__ W,
    const float* __restrict__ bias_sum, const int* __restrict__ row_list,
    const int* __restrict__ xmeta, float* __restrict__ out) {
    int xcd = blockIdx.x, slot = blockIdx.y, colt = blockIdx.z;
    const int* e = xmeta + (xcd * SLOTS + slot) * 3;
    int cond = e[0], rstart = e[1], rcnt = e[2];
    if (rcnt == 0) return;
    int col0 = colt * BN;

    __shared__ char lds[2 * BUFB];  // 48 KB double buffer -> 3 blocks/CU

    int tid  = threadIdx.x;
    int lane = tid & 63;
    int w    = tid >> 6;      // 0..3
    int wr   = w >> 1;        // M half (64 rows)
    int wc   = w & 1;         // N half (32 cols)
    int srow = lane >> 3;     // 0..7
    int scol = ((lane & 7) ^ srow) * 8;   // pre-swizzled global source col (A)

    const bf16* aS[4];
#pragma unroll
    for (int i = 0; i < 4; i++) {                 // A: 128 gathered x rows
        int tr = i * 32 + w * 8 + srow;
        int rr = (tr < rcnt) ? tr : 0;
        int grow = row_list[rstart + rr];
        aS[i] = xb + (size_t)grow * DIM + scol;
    }
    // B: thread -> W row (col0 + tid/4), k-segment (tid&3)*16 floats
    int brow = tid >> 2;                          // 0..63
    int kseg = tid & 3;
    const float* bW = W + (size_t)cond * DIM * DIM + (size_t)(col0 + brow) * DIM + kseg * 16;
    int g0 = kseg * 2;                            // first 16B granule of my 32B
    int bofs0 = ABYT + brow * 128 + ((g0 * 16) ^ ((brow & 7) << 4));
    int bofs1 = ABYT + brow * 128 + (((g0 + 1) * 16) ^ ((brow & 7) << 4));

    f32x4 acc[4][2];
#pragma unroll
    for (int m = 0; m < 4; m++)
#pragma unroll
        for (int n = 0; n < 2; n++) acc[m][n] = (f32x4){0.f, 0.f, 0.f, 0.f};

    int fr = lane & 15;
    int fq = lane >> 4;
    int off0 = (fq * 16) ^ ((fr & 7) << 4);
    int off1 = off0 ^ 64;

    float4 vb[4];   // staged fp32 B (16 floats)

    auto LOADB = [&](int k0) {
        const float4* p = (const float4*)(bW + k0);
#pragma unroll
        for (int j = 0; j < 4; j++) vb[j] = p[j];
    };
    auto WRITEB = [&](int buf) {
        bf16x8 o0, o1;
        o0[0] = (bf16)vb[0].x; o0[1] = (bf16)vb[0].y; o0[2] = (bf16)vb[0].z; o0[3] = (bf16)vb[0].w;
        o0[4] = (bf16)vb[1].x; o0[5] = (bf16)vb[1].y; o0[6] = (bf16)vb[1].z; o0[7] = (bf16)vb[1].w;
        o1[0] = (bf16)vb[2].x; o1[1] = (bf16)vb[2].y; o1[2] = (bf16)vb[2].z; o1[3] = (bf16)vb[2].w;
        o1[4] = (bf16)vb[3].x; o1[5] = (bf16)vb[3].y; o1[6] = (bf16)vb[3].z; o1[7] = (bf16)vb[3].w;
        *(bf16x8*)(lds + buf * BUFB + bofs0) = o0;
        *(bf16x8*)(lds + buf * BUFB + bofs1) = o1;
    };
    auto STAGEA = [&](int buf, int k0) {
#pragma unroll
        for (int i = 0; i < 4; i++)
            __builtin_amdgcn_global_load_lds((gbl_vp)(aS[i] + k0),
                (lds_vp)(lds + buf * BUFB + (i * 32 + w * 8) * 128), 16, 0, 0);
    };

    // prologue (issue order BL-before-A keeps vmcnt gates exact)
    LOADB(0);                                         // BL(0)
    STAGEA(0, 0);                                     // A(0)
    asm volatile("s_waitcnt vmcnt(4)" ::: "memory");  // BL(0) done
    WRITEB(0);
    LOADB(64);                                        // BL(1)
    STAGEA(1, 64);                                    // A(1)
    asm volatile("s_waitcnt lgkmcnt(0)" ::: "memory");// my B writes done

    for (int t = 0; t < NT; ++t) {
        if (t < NT - 1) asm volatile("s_waitcnt vmcnt(8)" ::: "memory");  // A(t) done
        else            asm volatile("s_waitcnt vmcnt(0)" ::: "memory");
        __builtin_amdgcn_s_barrier();   // buf t published (A + everyone's B)

        const char* bA = lds + (t & 1) * BUFB + (wr * 64 + fr) * 128;
        const char* bB = lds + (t & 1) * BUFB + ABYT + (wc * 32 + fr) * 128;
#pragma unroll
        for (int kk = 0; kk < 2; ++kk) {
            int ofs = kk ? off1 : off0;
            bf16x8 af[4], bv[2];
#pragma unroll
            for (int m = 0; m < 4; m++) af[m] = *(const bf16x8*)(bA + m * 2048 + ofs);
#pragma unroll
            for (int n = 0; n < 2; n++) bv[n] = *(const bf16x8*)(bB + n * 2048 + ofs);
            __builtin_amdgcn_s_setprio(1);
#pragma unroll
            for (int m = 0; m < 4; m++)
#pragma unroll
                for (int n = 0; n < 2; n++)
                    acc[m][n] = __builtin_amdgcn_mfma_f32_16x16x32_bf16(
                        af[m], bv[n], acc[m][n], 0, 0, 0);
            __builtin_amdgcn_s_setprio(0);
        }

        if (t + 1 < NT) {
            asm volatile("s_waitcnt vmcnt(4)" ::: "memory");  // BL(t+1) arrived
            WRITEB((t + 1) & 1);                              // into buf not being read
        }
        asm volatile("s_waitcnt lgkmcnt(0)" ::: "memory");    // reads + B writes retired
        __builtin_amdgcn_s_barrier();                         // buf cur free; B(t+1) published
        if (t + 2 < NT) {
            LOADB((t + 2) * 64);       // BL(t+2)
            STAGEA(t & 1, (t + 2) * 64);  // A(t+2) into just-freed buffer
        }
    }

    float bias[2];
#pragma unroll
    for (int n = 0; n < 2; n++) bias[n] = bias_sum[col0 + wc * 32 + n * 16 + fr];
#pragma unroll
    for (int m = 0; m < 4; m++) {
#pragma unroll
        for (int i = 0; i < 4; i++) {
            int rl = wr * 64 + m * 16 + fq * 4 + i;
            if (rl < rcnt) {
                int grow = row_list[rstart + rl];
                float* op = out + (size_t)grow * DIM + col0 + wc * 32 + fr;
#pragma unroll
                for (int n = 0; n < 2; n++) op[n * 16] = acc[m][n][i] + bias[n];
            }
        }
    }
}

// ---------------- naive fallback (only if ws too small) --------------------
__global__ void naive_kernel(const float* __restrict__ x, const int* __restrict__ ids,
                             const float* __restrict__ W, const float* __restrict__ b,
                             float* __restrict__ out) {
    int row = blockIdx.x;
    int c = ids[row];
    __shared__ float xs[DIM];
    for (int i = threadIdx.x; i < DIM; i += 256) xs[i] = x[(size_t)row * DIM + i];
    __syncthreads();
    const float* Wc = W + (size_t)c * DIM * DIM;
    for (int o = threadIdx.x; o < DIM; o += 256) {
        float s = 0.f;
        const float* wrp = Wc + (size_t)o * DIM;
        for (int i = 0; i < DIM; i++) s += xs[i] * wrp[i];
        float bs = 0.f;
#pragma unroll
        for (int cc = 0; cc < NC; cc++) bs += b[cc * DIM + o];
        out[(size_t)row * DIM + o] = s + bs;
    }
}

extern "C" void kernel_launch(void* const* d_in, const int* in_sizes, int n_in,
                              void* d_out, int out_size, void* d_ws, size_t ws_size,
                              hipStream_t stream) {
    const float* x   = (const float*)d_in[0];
    const int*   ids = (const int*)d_in[1];
    const float* W   = (const float*)d_in[2];
    const float* b   = (const float*)d_in[3];
    float*       out = (float*)d_out;

    size_t xb_off   = 0;
    size_t xb_sz    = (size_t)B_ROWS * DIM * 2;
    size_t bias_off = (xb_off + xb_sz + 255) & ~(size_t)255;
    size_t rl_off   = (bias_off + DIM * 4 + 255) & ~(size_t)255;
    size_t meta_off = (rl_off + B_ROWS * 4 + 255) & ~(size_t)255;
    size_t need     = meta_off + (size_t)NXCD * SLOTS * 3 * 4;

    if (ws_size < need) {
        naive_kernel<<<dim3(B_ROWS), dim3(256), 0, stream>>>(x, ids, W, b, out);
        return;
    }

    char* ws = (char*)d_ws;
    bf16*  xb       = (bf16*)(ws + xb_off);
    float* bias_sum = (float*)(ws + bias_off);
    int*   row_list = (int*)(ws + rl_off);
    int*   xmeta    = (int*)(ws + meta_off);

    prep_kernel<<<dim3(257), dim3(1024), 0, stream>>>(x, ids, b, xb,
                                                      row_list, xmeta, bias_sum);
    gemm_kernel<<<dim3(NXCD, SLOTS, DIM / BN), dim3(256), 0, stream>>>(
        xb, W, bias_sum, row_list, xmeta, out);
}

// Round 14
// 52.679 us; speedup vs baseline: 1.1894x; 1.1894x over previous
//
#include <hip/hip_runtime.h>
#include <hip/hip_bf16.h>
#include <cstdint>

#define B_ROWS 8192
#define DIM    1024
#define NC     8
#define NXCD   8
#define SLOTS  16    // per-XCD 128-row tile slots
#define BM     128
#define BN     64
#define NT     16    // K tiles (DIM/64)

typedef __bf16 bf16;
typedef __bf16 bf16x4 __attribute__((ext_vector_type(4)));
typedef __bf16 bf16x8 __attribute__((ext_vector_type(8)));
typedef float  f32x4  __attribute__((ext_vector_type(4)));

typedef __attribute__((address_space(3))) void* lds_vp;
typedef const __attribute__((address_space(1))) void* gbl_vp;

#define BUFB 24576   // LDS bytes per buffer: (128+64)*64*2
#define ABYT 16384   // A region bytes: 128*64*2

// ---------------- fused prep: block 0 = route, blocks 1..512 = cvt ---------
#define XF4 (B_ROWS * DIM / 4)
__global__ __launch_bounds__(1024) void prep_kernel(
    const float* __restrict__ x, const float* __restrict__ W,
    const int* __restrict__ ids, const float* __restrict__ b,
    bf16* __restrict__ xb, bf16* __restrict__ wb,
    int* __restrict__ row_list, int* __restrict__ xmeta,
    float* __restrict__ bias_sum) {
    if (blockIdx.x != 0) {
        size_t base = (size_t)(blockIdx.x - 1) * 8192 + threadIdx.x;
        const float4* src;
        bf16* dst;
        if (base < (size_t)XF4) { src = (const float4*)x; dst = xb; }
        else                    { src = (const float4*)W; dst = wb; base -= (size_t)XF4; }
        float4 v[8];
#pragma unroll
        for (int k = 0; k < 8; k++) v[k] = src[base + (size_t)k * 1024];
#pragma unroll
        for (int k = 0; k < 8; k++) {
            bf16x4 o;
            o[0] = (bf16)v[k].x; o[1] = (bf16)v[k].y;
            o[2] = (bf16)v[k].z; o[3] = (bf16)v[k].w;
            *(bf16x4*)(dst + 4 * (base + (size_t)k * 1024)) = o;
        }
        return;
    }
    // routing (block 0): 1024 threads, scan-based, no atomics
    __shared__ int wtot_s[16][NC];
    __shared__ int cnt_s[NC];
    __shared__ int off_s[NC];
    __shared__ int used_s[NXCD];
    __shared__ int novf_s[NC];
    int tid = threadIdx.x, lane = tid & 63, wv = tid >> 6;
    const int per = B_ROWS / 1024;  // 8
    int base = tid * per;

    if (tid < NXCD * SLOTS) xmeta[tid * 3 + 2] = 0;

    const int4* idv = (const int4*)(ids + base);
    int4 v0 = idv[0], v1 = idv[1];
    int myid[8] = {v0.x, v0.y, v0.z, v0.w, v1.x, v1.y, v1.z, v1.w};
    unsigned long long p0 = 0, p1 = 0;
#pragma unroll
    for (int q = 0; q < 8; q++) {
        int id = myid[q];
        unsigned long long one = 1ull << ((id & 3) << 4);
        if (id < 4) p0 += one; else p1 += one;
    }
    unsigned long long i0 = p0, i1 = p1;
#pragma unroll
    for (int d = 1; d < 64; d <<= 1) {
        unsigned long long u0 = __shfl_up(i0, d, 64);
        unsigned long long u1 = __shfl_up(i1, d, 64);
        if (lane >= d) { i0 += u0; i1 += u1; }
    }
    unsigned long long e0 = i0 - p0, e1 = i1 - p1;
    unsigned long long t0 = __shfl(i0, 63, 64), t1 = __shfl(i1, 63, 64);
    if (lane == 0) {
#pragma unroll
        for (int c = 0; c < 4; c++) {
            wtot_s[wv][c]     = (int)((t0 >> (c << 4)) & 0xFFFF);
            wtot_s[wv][c + 4] = (int)((t1 >> (c << 4)) & 0xFFFF);
        }
    }
    __syncthreads();
    if (tid < NC) {
        int acc = 0;
        for (int w2 = 0; w2 < 16; w2++) { int t = wtot_s[w2][tid]; wtot_s[w2][tid] = acc; acc += t; }
        cnt_s[tid] = acc;
    }
    __syncthreads();
    if (tid < NC) {
        int acc = 0;
        for (int c2 = 0; c2 < tid; c2++) acc += cnt_s[c2];
        off_s[tid] = acc;
    }
    __syncthreads();
    if (tid < 16 * NC) wtot_s[tid >> 3][tid & 7] += off_s[tid & 7];
    __syncthreads();

    if (tid < NC) {  // primary 128-row tiles: condition c -> XCD c
        int c = tid, n = cnt_s[c];
        int tc = (n + BM - 1) >> 7;
        int prim = tc < SLOTS ? tc : SLOTS;
        for (int t = 0; t < prim; t++) {
            int* e = xmeta + (c * SLOTS + t) * 3;
            int rc = n - t * BM; if (rc > BM) rc = BM;
            e[0] = c; e[1] = off_s[c] + t * BM; e[2] = rc;
        }
        used_s[c] = prim;
        novf_s[c] = tc - prim;
    }
    {
        float s = 0.f;
#pragma unroll
        for (int c = 0; c < NC; c++) s += b[c * DIM + tid];
        bias_sum[tid] = s;
    }
    __syncthreads();
    if (tid == 0) {  // overflow tiles (condition with >SLOTS*128 rows)
        int k = 0;
        for (int c = 0; c < NC; c++) {
            for (int t = 0; t < novf_s[c]; t++) {
                for (;;) {
                    int xx = k >> 4, s = k & (SLOTS - 1); k++;
                    if (s >= used_s[xx]) {
                        int* e = xmeta + (xx * SLOTS + s) * 3;
                        int rc = cnt_s[c] - (SLOTS + t) * BM; if (rc > BM) rc = BM;
                        e[0] = c; e[1] = off_s[c] + (SLOTS + t) * BM; e[2] = rc;
                        break;
                    }
                }
            }
        }
    }
    unsigned long long r0 = 0, r1 = 0;
#pragma unroll
    for (int j = 0; j < per; j++) {
        int id = myid[j];
        int sh = (id & 3) << 4;
        unsigned long long run = (id < 4) ? r0 : r1;
        unsigned long long exc = (id < 4) ? e0 : e1;
        int p = wtot_s[wv][id] + (int)((exc >> sh) & 0xFFFF) + (int)((run >> sh) & 0xFFFF);
        row_list[p] = base + j;
        unsigned long long one = 1ull << sh;
        if (id < 4) r0 += one; else r1 += one;
    }
}

// ---------------- grouped GEMM: 128x64 tile, 4 waves, 3 blocks/CU ----------
// R12-proven: 2-phase counted-vmcnt body at high block-level TLP.
// Per wave: 64x32 output, acc[4][2]; stage 4xA + 2xB gload_lds per K-tile.
__global__ __launch_bounds__(256, 3) void gemm_kernel(
    const bf16* __restrict__ xb, const bf16* __restrict__ wb,
    const float* __restrict__ bias_sum, const int* __restrict__ row_list,
    const int* __restrict__ xmeta, float* __restrict__ out) {
    int xcd = blockIdx.x, slot = blockIdx.y, colt = blockIdx.z;
    const int* e = xmeta + (xcd * SLOTS + slot) * 3;
    int cond = e[0], rstart = e[1], rcnt = e[2];
    if (rcnt == 0) return;
    int col0 = colt * BN;

    __shared__ char lds[2 * BUFB];  // 48 KB double buffer -> 3 blocks/CU

    int tid  = threadIdx.x;
    int lane = tid & 63;
    int w    = tid >> 6;      // 0..3
    int wr   = w >> 1;        // M half (64 rows)
    int wc   = w & 1;         // N half (32 cols)
    int srow = lane >> 3;     // 0..7
    int scol = ((lane & 7) ^ srow) * 8;   // pre-swizzled global source col

    const bf16 *aS[4], *bS[2];
#pragma unroll
    for (int i = 0; i < 4; i++) {                 // A: 128 rows
        int tr = i * 32 + w * 8 + srow;
        int rr = (tr < rcnt) ? tr : 0;
        int grow = row_list[rstart + rr];
        aS[i] = xb + (size_t)grow * DIM + scol;
    }
#pragma unroll
    for (int i = 0; i < 2; i++) {                 // B: 64 W rows
        int br = i * 32 + w * 8 + srow;
        bS[i] = wb + (size_t)cond * DIM * DIM + (size_t)(col0 + br) * DIM + scol;
    }

    f32x4 acc[4][2];
#pragma unroll
    for (int m = 0; m < 4; m++)
#pragma unroll
        for (int n = 0; n < 2; n++) acc[m][n] = (f32x4){0.f, 0.f, 0.f, 0.f};

    int fr = lane & 15;
    int fq = lane >> 4;
    int off0 = (fq * 16) ^ ((fr & 7) << 4);
    int off1 = off0 ^ 64;

    auto stage = [&](int buf, int k0) {
#pragma unroll
        for (int i = 0; i < 4; i++)
            __builtin_amdgcn_global_load_lds((gbl_vp)(aS[i] + k0),
                (lds_vp)(lds + buf * BUFB + (i * 32 + w * 8) * 128), 16, 0, 0);
#pragma unroll
        for (int i = 0; i < 2; i++)
            __builtin_amdgcn_global_load_lds((gbl_vp)(bS[i] + k0),
                (lds_vp)(lds + buf * BUFB + ABYT + (i * 32 + w * 8) * 128), 16, 0, 0);
    };

    stage(0, 0);
    stage(1, 64);   // 12 loads/thread in flight

    for (int t = 0; t < NT; ++t) {
        if (t < NT - 1) asm volatile("s_waitcnt vmcnt(6)" ::: "memory");
        else            asm volatile("s_waitcnt vmcnt(0)" ::: "memory");
        __builtin_amdgcn_s_barrier();

        const char* bA = lds + (t & 1) * BUFB + (wr * 64 + fr) * 128;
        const char* bB = lds + (t & 1) * BUFB + ABYT + (wc * 32 + fr) * 128;
#pragma unroll
        for (int kk = 0; kk < 2; ++kk) {
            int ofs = kk ? off1 : off0;
            bf16x8 af[4], bv[2];
#pragma unroll
            for (int m = 0; m < 4; m++) af[m] = *(const bf16x8*)(bA + m * 2048 + ofs);
#pragma unroll
            for (int n = 0; n < 2; n++) bv[n] = *(const bf16x8*)(bB + n * 2048 + ofs);
            __builtin_amdgcn_s_setprio(1);
#pragma unroll
            for (int m = 0; m < 4; m++)
#pragma unroll
                for (int n = 0; n < 2; n++)
                    acc[m][n] = __builtin_amdgcn_mfma_f32_16x16x32_bf16(
                        af[m], bv[n], acc[m][n], 0, 0, 0);
            __builtin_amdgcn_s_setprio(0);
        }

        asm volatile("s_waitcnt lgkmcnt(0)" ::: "memory");
        __builtin_amdgcn_s_barrier();
        if (t + 2 < NT) stage(t & 1, (t + 2) * 64);
    }

    float bias[2];
#pragma unroll
    for (int n = 0; n < 2; n++) bias[n] = bias_sum[col0 + wc * 32 + n * 16 + fr];
#pragma unroll
    for (int m = 0; m < 4; m++) {
#pragma unroll
        for (int i = 0; i < 4; i++) {
            int rl = wr * 64 + m * 16 + fq * 4 + i;
            if (rl < rcnt) {
                int grow = row_list[rstart + rl];
                float* op = out + (size_t)grow * DIM + col0 + wc * 32 + fr;
#pragma unroll
                for (int n = 0; n < 2; n++) op[n * 16] = acc[m][n][i] + bias[n];
            }
        }
    }
}

// ---------------- naive fallback (only if ws too small) --------------------
__global__ void naive_kernel(const float* __restrict__ x, const int* __restrict__ ids,
                             const float* __restrict__ W, const float* __restrict__ b,
                             float* __restrict__ out) {
    int row = blockIdx.x;
    int c = ids[row];
    __shared__ float xs[DIM];
    for (int i = threadIdx.x; i < DIM; i += 256) xs[i] = x[(size_t)row * DIM + i];
    __syncthreads();
    const float* Wc = W + (size_t)c * DIM * DIM;
    for (int o = threadIdx.x; o < DIM; o += 256) {
        float s = 0.f;
        const float* wrp = Wc + (size_t)o * DIM;
        for (int i = 0; i < DIM; i++) s += xs[i] * wrp[i];
        float bs = 0.f;
#pragma unroll
        for (int cc = 0; cc < NC; cc++) bs += b[cc * DIM + o];
        out[(size_t)row * DIM + o] = s + bs;
    }
}

extern "C" void kernel_launch(void* const* d_in, const int* in_sizes, int n_in,
                              void* d_out, int out_size, void* d_ws, size_t ws_size,
                              hipStream_t stream) {
    const float* x   = (const float*)d_in[0];
    const int*   ids = (const int*)d_in[1];
    const float* W   = (const float*)d_in[2];
    const float* b   = (const float*)d_in[3];
    float*       out = (float*)d_out;

    size_t xb_off   = 0;
    size_t xb_sz    = (size_t)B_ROWS * DIM * 2;
    size_t wb_off   = (xb_off + xb_sz + 255) & ~(size_t)255;
    size_t wb_sz    = (size_t)NC * DIM * DIM * 2;
    size_t bias_off = (wb_off + wb_sz + 255) & ~(size_t)255;
    size_t rl_off   = (bias_off + DIM * 4 + 255) & ~(size_t)255;
    size_t meta_off = (rl_off + B_ROWS * 4 + 255) & ~(size_t)255;
    size_t need     = meta_off + (size_t)NXCD * SLOTS * 3 * 4;

    if (ws_size < need) {
        naive_kernel<<<dim3(B_ROWS), dim3(256), 0, stream>>>(x, ids, W, b, out);
        return;
    }

    char* ws = (char*)d_ws;
    bf16*  xb       = (bf16*)(ws + xb_off);
    bf16*  wbf      = (bf16*)(ws + wb_off);
    float* bias_sum = (float*)(ws + bias_off);
    int*   row_list = (int*)(ws + rl_off);
    int*   xmeta    = (int*)(ws + meta_off);

    prep_kernel<<<dim3(513), dim3(1024), 0, stream>>>(x, W, ids, b, xb, wbf,
                                                      row_list, xmeta, bias_sum);
    gemm_kernel<<<dim3(NXCD, SLOTS, DIM / BN), dim3(256), 0, stream>>>(
        xb, wbf, bias_sum, row_list, xmeta, out);
}